// Round 6
// baseline (267.048 us; speedup 1.0000x reference)
//
#include <hip/hip_runtime.h>

// SSIM loss v6 — 2 columns/thread, full-width blocks, even/odd LDS split:
//   - thread t owns cols 2t,2t+1 of a 512-wide x SH-tall tile -> per-output
//     overhead (prefetch addr math, staging, barriers, loop) halves vs v5
//   - prefetch = 4 coalesced float2 loads; NO x-guards (pads live in LDS)
//   - LDS de-interleaved into even/odd column arrays so both columns' taps
//     are consecutive-entry ds_read_b128 (contiguous 128B/8 lanes, 0 conflicts)
//   - v3's validated row-pair pk-f32 math: h-conv 7 pk/tap, v-conv pk-dot
//     with {g2m,g2m+1}/{g2m-1,g2m} weight pairs, rings 6-deep (x2 cols)
//   - __launch_bounds__(256,2): rings need ~190 VGPR; (256,4+) spills (R4),
//     (256,4) also degrades scheduling (R5). Do not tighten.
// B=32, C=3, H=W=512 fp32; zero padding (pad=5) matches lax conv semantics.

typedef float v2f __attribute__((ext_vector_type(2)));
typedef float v4f __attribute__((ext_vector_type(4)));

constexpr int IMG    = 512;
constexpr int TPB    = 256;          // threads/block; 2 cols/thread
constexpr int SH     = 64;           // output rows per block
constexpr int NPAIR  = 37;           // input row-pairs streamed (74 rows)
constexpr int LW     = 264;          // entries per parity array (4 pad + 256 + 4 pad)
constexpr int PLANES = 32 * 3;       // 96
constexpr int NBLK   = (IMG / SH) * PLANES;   // 768
constexpr double N_PIX = 25165824.0; // 32*3*512*512

__global__ __launch_bounds__(TPB, 2) void ssim_map_kernel(
    const float* __restrict__ img1, const float* __restrict__ img2,
    double* __restrict__ partial)
{
    constexpr float GW[11] = {
        0.0010283801f, 0.0075987583f, 0.0360007721f, 0.1093607008f,
        0.2130055439f, 0.2660117257f, 0.2130055439f, 0.1093607008f,
        0.0360007721f, 0.0075987583f, 0.0010283801f };
    constexpr float GWp[13] = {      // GWp[k+1] = GW[k], zero-padded ends
        0.0f,
        0.0010283801f, 0.0075987583f, 0.0360007721f, 0.1093607008f,
        0.2130055439f, 0.2660117257f, 0.2130055439f, 0.1093607008f,
        0.0360007721f, 0.0075987583f, 0.0010283801f,
        0.0f };

    // sE[b][u] = col 2(u-4)   as {i1_rA, i1_rB, i2_rA, i2_rB}
    // sO[b][u] = col 2(u-4)+1 as {i1_rA, i1_rB, i2_rA, i2_rB}
    __shared__ v4f  sE[3][LW];
    __shared__ v4f  sO[3][LW];
    __shared__ float wsum[TPB / 64];

    const int tid   = threadIdx.x;
    const int y0    = blockIdx.x * SH;
    const int plane = blockIdx.y;

    const float* p1 = img1 + (size_t)plane * IMG * IMG;
    const float* p2 = img2 + (size_t)plane * IMG * IMG;

    // zero the column-pad entries once: idx {0..3, 260..263} in each of
    // 3 buffers x 2 parity arrays = 48 entries; never overwritten later.
    if (tid < 48) {
        const int b = tid >> 4, r = tid & 15, arr = r >> 3, p = r & 7;
        const int idx = (p < 4) ? p : (256 + p);      // 0..3 or 260..263
        if (arr) sO[b][idx] = v4f{0.f, 0.f, 0.f, 0.f};
        else     sE[b][idx] = v4f{0.f, 0.f, 0.f, 0.f};
    }

    // 6-deep row-pair rings, 5 quantities x 2 columns (A=even col, B=odd col)
    v2f rA1[6], rA2[6], rA11[6], rA22[6], rA12[6];
    v2f rB1[6], rB2[6], rB11[6], rB22[6], rB12[6];
    v2f accv = {0.0f, 0.0f};

    float2 pa1, pb1, pa2, pb2;   // prefetched {col2t, col2t+1} per row/img
    const int c0 = 2 * tid;

    auto prefetch = [&](int i) {
        const int  rA  = y0 - 5 + 2 * i;
        const int  rB  = rA + 1;
        const bool aok = (unsigned)rA < (unsigned)IMG;   // wave-uniform
        const bool bok = (unsigned)rB < (unsigned)IMG;
        const size_t oA = aok ? (size_t)rA * IMG : 0;    // clamped, masked below
        const size_t oB = bok ? (size_t)rB * IMG : 0;
        pa1 = *(const float2*)(p1 + oA + c0);
        pb1 = *(const float2*)(p1 + oB + c0);
        pa2 = *(const float2*)(p2 + oA + c0);
        pb2 = *(const float2*)(p2 + oB + c0);
        if (!aok) { pa1 = make_float2(0.f, 0.f); pa2 = make_float2(0.f, 0.f); }
        if (!bok) { pb1 = make_float2(0.f, 0.f); pb2 = make_float2(0.f, 0.f); }
    };

    prefetch(0);

    for (int ib = 0; ib < NPAIR; ib += 6) {
#pragma unroll
        for (int j = 0; j < 6; ++j) {
            const int i = ib + j;
            const int s = j % 3;
            if (i < NPAIR) {
                sE[s][tid + 4] = v4f{pa1.x, pb1.x, pa2.x, pb2.x};
                sO[s][tid + 4] = v4f{pa1.y, pb1.y, pa2.y, pb2.y};

                if (i + 1 < NPAIR) prefetch(i + 1);

                __syncthreads();   // RAW on slot s; triple buffer kills WAR

                // h-conv, both columns.
                //   colA=2t taps: k even -> O[t+1+k/2], k odd -> E[t+2+(k-1)/2]
                //   colB=2t+1   : k even -> E[t+2+k/2], k odd -> O[t+2+(k-1)/2]
                const v4f* eb = &sE[s][tid + 2];
                const v4f* ob = &sO[s][tid + 1];
                v2f a1A={0,0}, a2A={0,0}, a11A={0,0}, a22A={0,0}, a12A={0,0};
                v2f a1B={0,0}, a2B={0,0}, a11B={0,0}, a22B={0,0}, a12B={0,0};
#pragma unroll
                for (int k = 0; k < 11; ++k) {
                    const float g = GW[k];
                    const v4f sA = (k & 1) ? eb[(k - 1) >> 1] : ob[k >> 1];
                    const v4f sB = (k & 1) ? ob[(k + 1) >> 1] : eb[k >> 1];
                    {   const v2f x1 = __builtin_shufflevector(sA, sA, 0, 1);
                        const v2f x2 = __builtin_shufflevector(sA, sA, 2, 3);
                        const v2f t1 = g * x1;
                        const v2f t2 = g * x2;
                        a1A += t1; a2A += t2;
                        a11A = __builtin_elementwise_fma(t1, x1, a11A);
                        a22A = __builtin_elementwise_fma(t2, x2, a22A);
                        a12A = __builtin_elementwise_fma(t1, x2, a12A); }
                    {   const v2f x1 = __builtin_shufflevector(sB, sB, 0, 1);
                        const v2f x2 = __builtin_shufflevector(sB, sB, 2, 3);
                        const v2f t1 = g * x1;
                        const v2f t2 = g * x2;
                        a1B += t1; a2B += t2;
                        a11B = __builtin_elementwise_fma(t1, x1, a11B);
                        a22B = __builtin_elementwise_fma(t2, x2, a22B);
                        a12B = __builtin_elementwise_fma(t1, x2, a12B); }
                }
                rA1[j] = a1A;  rA2[j] = a2A;  rA11[j] = a11A;
                rA22[j] = a22A; rA12[j] = a12A;
                rB1[j] = a1B;  rB2[j] = a2B;  rB11[j] = a11B;
                rB22[j] = a22B; rB12[j] = a12B;
            }

            if (i >= 5 && i < NPAIR) {
                // v-conv + SSIM, one column at a time (caps live partials).
                // ring entry m (input pair q+m, q=i-5) sits at slot (j+1+m)%6
#pragma unroll
                for (int col = 0; col < 2; ++col) {
                    const v2f* g1  = col ? rB1  : rA1;
                    const v2f* g2  = col ? rB2  : rA2;
                    const v2f* g11 = col ? rB11 : rA11;
                    const v2f* g22 = col ? rB22 : rA22;
                    const v2f* g12 = col ? rB12 : rA12;
                    v2f sx1={0,0}, sy1={0,0}, sx2={0,0}, sy2={0,0};
                    v2f sx11={0,0}, sy11={0,0}, sx22={0,0}, sy22={0,0};
                    v2f sx12={0,0}, sy12={0,0};
#pragma unroll
                    for (int m = 0; m < 6; ++m) {
                        const int q = (j + 1 + m) % 6;
                        const v2f wx = { GWp[2*m + 1], GWp[2*m + 2] };
                        const v2f wy = { GWp[2*m],     GWp[2*m + 1] };
                        sx1  = __builtin_elementwise_fma(wx, g1[q],  sx1);
                        sy1  = __builtin_elementwise_fma(wy, g1[q],  sy1);
                        sx2  = __builtin_elementwise_fma(wx, g2[q],  sx2);
                        sy2  = __builtin_elementwise_fma(wy, g2[q],  sy2);
                        sx11 = __builtin_elementwise_fma(wx, g11[q], sx11);
                        sy11 = __builtin_elementwise_fma(wy, g11[q], sy11);
                        sx22 = __builtin_elementwise_fma(wx, g22[q], sx22);
                        sy22 = __builtin_elementwise_fma(wy, g22[q], sy22);
                        sx12 = __builtin_elementwise_fma(wx, g12[q], sx12);
                        sy12 = __builtin_elementwise_fma(wy, g12[q], sy12);
                    }
                    const v2f m1  = { sx1.x + sx1.y,  sy1.x + sy1.y };
                    const v2f m2  = { sx2.x + sx2.y,  sy2.x + sy2.y };
                    const v2f e11 = { sx11.x + sx11.y, sy11.x + sy11.y };
                    const v2f e22 = { sx22.x + sx22.y, sy22.x + sy22.y };
                    const v2f e12 = { sx12.x + sx12.y, sy12.x + sy12.y };

                    const v2f mu11 = m1 * m1;
                    const v2f mu22 = m2 * m2;
                    const v2f mu12 = m1 * m2;
                    const v2f zero = {0.0f, 0.0f};
                    const v2f one  = {1.0f, 1.0f};
                    const v2f sg1  = __builtin_elementwise_max(e11 - mu11, zero);
                    const v2f sg2  = __builtin_elementwise_max(e22 - mu22, zero);
                    const v2f sg12 = e12 - mu12;
                    const v2f num = (2.0f * mu12 + 1e-4f) * (2.0f * sg12 + 9e-4f);
                    const v2f den = (mu11 + mu22 + 1e-4f) * (sg1 + sg2 + 9e-4f);
                    v2f v = { num.x * __builtin_amdgcn_rcpf(den.x),
                              num.y * __builtin_amdgcn_rcpf(den.y) };
                    v = __builtin_elementwise_min(
                            __builtin_elementwise_max(v, zero), one);
                    accv += v;
                }
            }
        }
    }

    float acc = accv.x + accv.y;
#pragma unroll
    for (int off = 32; off > 0; off >>= 1)
        acc += __shfl_down(acc, off, 64);
    if ((tid & 63) == 0) wsum[tid >> 6] = acc;
    __syncthreads();
    if (tid == 0) {
        double blocksum = 0.0;
#pragma unroll
        for (int w = 0; w < TPB / 64; ++w) blocksum += (double)wsum[w];
        const int bid = blockIdx.x + (IMG / SH) * blockIdx.y;
        partial[bid] = blocksum;   // every slot written: no init needed
    }
}

__global__ __launch_bounds__(256) void ssim_finalize_kernel(
    const double* __restrict__ partial, float* __restrict__ out)
{
    __shared__ double wsum[4];
    const int tid = threadIdx.x;
    double s = 0.0;
#pragma unroll
    for (int k = 0; k < NBLK / 256; ++k) s += partial[tid + 256 * k];
#pragma unroll
    for (int off = 32; off > 0; off >>= 1)
        s += __shfl_down(s, off, 64);
    if ((tid & 63) == 0) wsum[tid >> 6] = s;
    __syncthreads();
    if (tid == 0) {
        double t = wsum[0] + wsum[1] + wsum[2] + wsum[3];
        out[0] = 1.0f - (float)(t / N_PIX);
    }
}

extern "C" void kernel_launch(void* const* d_in, const int* in_sizes, int n_in,
                              void* d_out, int out_size, void* d_ws, size_t ws_size,
                              hipStream_t stream) {
    const float* img1 = (const float*)d_in[0];
    const float* img2 = (const float*)d_in[1];
    float* out = (float*)d_out;
    double* parts = (double*)d_ws;   // 768 doubles = 6 KB

    dim3 grid(IMG / SH, PLANES);     // 8 x 96 = 768 blocks (full-width tiles)
    ssim_map_kernel<<<grid, TPB, 0, stream>>>(img1, img2, parts);
    ssim_finalize_kernel<<<1, 256, 0, stream>>>(parts, out);
}

// Round 7
// 252.959 us; speedup vs baseline: 1.0557x; 1.0557x over previous
//
#include <hip/hip_runtime.h>

// SSIM loss v7 — R6 datapath (2 cols/thread, even/odd LDS, pk-f32 row pairs)
// with SH=32: grid 1536 blocks (6/CU offered) to fix R6's grid-limited
// residency (768 blocks = 3/CU -> 17% occupancy, 52% idle).
//   - VGPR ~96 -> 4 waves/SIMD granule -> 4 blocks/CU hardware cap
//   - cost: y-halo streaming 42 rows per 32 outputs (+13% row work)
//   - __launch_bounds__(256,2): do NOT tighten (R4 spill, R5 sched loss)
// B=32, C=3, H=W=512 fp32; zero padding (pad=5) matches lax conv semantics.

typedef float v2f __attribute__((ext_vector_type(2)));
typedef float v4f __attribute__((ext_vector_type(4)));

constexpr int IMG    = 512;
constexpr int TPB    = 256;          // threads/block; 2 cols/thread
constexpr int SH     = 32;           // output rows per block
constexpr int NPAIR  = (SH + 10) / 2;  // 21 input row-pairs streamed
constexpr int LW     = 264;          // entries per parity array (4+256+4)
constexpr int PLANES = 32 * 3;       // 96
constexpr int NBLK   = (IMG / SH) * PLANES;   // 1536
constexpr double N_PIX = 25165824.0; // 32*3*512*512

__global__ __launch_bounds__(TPB, 2) void ssim_map_kernel(
    const float* __restrict__ img1, const float* __restrict__ img2,
    double* __restrict__ partial)
{
    constexpr float GW[11] = {
        0.0010283801f, 0.0075987583f, 0.0360007721f, 0.1093607008f,
        0.2130055439f, 0.2660117257f, 0.2130055439f, 0.1093607008f,
        0.0360007721f, 0.0075987583f, 0.0010283801f };
    constexpr float GWp[13] = {      // GWp[k+1] = GW[k], zero-padded ends
        0.0f,
        0.0010283801f, 0.0075987583f, 0.0360007721f, 0.1093607008f,
        0.2130055439f, 0.2660117257f, 0.2130055439f, 0.1093607008f,
        0.0360007721f, 0.0075987583f, 0.0010283801f,
        0.0f };

    // sE[b][u] = col 2(u-4)   as {i1_rA, i1_rB, i2_rA, i2_rB}
    // sO[b][u] = col 2(u-4)+1 as {i1_rA, i1_rB, i2_rA, i2_rB}
    __shared__ v4f  sE[3][LW];
    __shared__ v4f  sO[3][LW];
    __shared__ float wsum[TPB / 64];

    const int tid   = threadIdx.x;
    const int y0    = blockIdx.x * SH;
    const int plane = blockIdx.y;

    const float* p1 = img1 + (size_t)plane * IMG * IMG;
    const float* p2 = img2 + (size_t)plane * IMG * IMG;

    // zero the column-pad entries once: idx {0..3, 260..263} in each of
    // 3 buffers x 2 parity arrays = 48 entries; never overwritten later.
    if (tid < 48) {
        const int b = tid >> 4, r = tid & 15, arr = r >> 3, p = r & 7;
        const int idx = (p < 4) ? p : (256 + p);      // 0..3 or 260..263
        if (arr) sO[b][idx] = v4f{0.f, 0.f, 0.f, 0.f};
        else     sE[b][idx] = v4f{0.f, 0.f, 0.f, 0.f};
    }

    // 6-deep row-pair rings, 5 quantities x 2 columns (A=even col, B=odd col)
    v2f rA1[6], rA2[6], rA11[6], rA22[6], rA12[6];
    v2f rB1[6], rB2[6], rB11[6], rB22[6], rB12[6];
    v2f accv = {0.0f, 0.0f};

    float2 pa1, pb1, pa2, pb2;   // prefetched {col2t, col2t+1} per row/img
    const int c0 = 2 * tid;

    auto prefetch = [&](int i) {
        const int  rA  = y0 - 5 + 2 * i;
        const int  rB  = rA + 1;
        const bool aok = (unsigned)rA < (unsigned)IMG;   // wave-uniform
        const bool bok = (unsigned)rB < (unsigned)IMG;
        const size_t oA = aok ? (size_t)rA * IMG : 0;    // clamped, masked below
        const size_t oB = bok ? (size_t)rB * IMG : 0;
        pa1 = *(const float2*)(p1 + oA + c0);
        pb1 = *(const float2*)(p1 + oB + c0);
        pa2 = *(const float2*)(p2 + oA + c0);
        pb2 = *(const float2*)(p2 + oB + c0);
        if (!aok) { pa1 = make_float2(0.f, 0.f); pa2 = make_float2(0.f, 0.f); }
        if (!bok) { pb1 = make_float2(0.f, 0.f); pb2 = make_float2(0.f, 0.f); }
    };

    prefetch(0);

    for (int ib = 0; ib < NPAIR; ib += 6) {
#pragma unroll
        for (int j = 0; j < 6; ++j) {
            const int i = ib + j;
            const int s = j % 3;
            if (i < NPAIR) {
                sE[s][tid + 4] = v4f{pa1.x, pb1.x, pa2.x, pb2.x};
                sO[s][tid + 4] = v4f{pa1.y, pb1.y, pa2.y, pb2.y};

                if (i + 1 < NPAIR) prefetch(i + 1);

                __syncthreads();   // RAW on slot s; triple buffer kills WAR

                // h-conv, both columns.
                //   colA=2t taps: k even -> O[t+1+k/2], k odd -> E[t+2+(k-1)/2]
                //   colB=2t+1   : k even -> E[t+2+k/2], k odd -> O[t+2+(k-1)/2]
                const v4f* eb = &sE[s][tid + 2];
                const v4f* ob = &sO[s][tid + 1];
                v2f a1A={0,0}, a2A={0,0}, a11A={0,0}, a22A={0,0}, a12A={0,0};
                v2f a1B={0,0}, a2B={0,0}, a11B={0,0}, a22B={0,0}, a12B={0,0};
#pragma unroll
                for (int k = 0; k < 11; ++k) {
                    const float g = GW[k];
                    const v4f sA = (k & 1) ? eb[(k - 1) >> 1] : ob[k >> 1];
                    const v4f sB = (k & 1) ? ob[(k + 1) >> 1] : eb[k >> 1];
                    {   const v2f x1 = __builtin_shufflevector(sA, sA, 0, 1);
                        const v2f x2 = __builtin_shufflevector(sA, sA, 2, 3);
                        const v2f t1 = g * x1;
                        const v2f t2 = g * x2;
                        a1A += t1; a2A += t2;
                        a11A = __builtin_elementwise_fma(t1, x1, a11A);
                        a22A = __builtin_elementwise_fma(t2, x2, a22A);
                        a12A = __builtin_elementwise_fma(t1, x2, a12A); }
                    {   const v2f x1 = __builtin_shufflevector(sB, sB, 0, 1);
                        const v2f x2 = __builtin_shufflevector(sB, sB, 2, 3);
                        const v2f t1 = g * x1;
                        const v2f t2 = g * x2;
                        a1B += t1; a2B += t2;
                        a11B = __builtin_elementwise_fma(t1, x1, a11B);
                        a22B = __builtin_elementwise_fma(t2, x2, a22B);
                        a12B = __builtin_elementwise_fma(t1, x2, a12B); }
                }
                rA1[j] = a1A;  rA2[j] = a2A;  rA11[j] = a11A;
                rA22[j] = a22A; rA12[j] = a12A;
                rB1[j] = a1B;  rB2[j] = a2B;  rB11[j] = a11B;
                rB22[j] = a22B; rB12[j] = a12B;
            }

            if (i >= 5 && i < NPAIR) {
                // v-conv + SSIM, one column at a time (caps live partials).
                // ring entry m (input pair q+m, q=i-5) sits at slot (j+1+m)%6
#pragma unroll
                for (int col = 0; col < 2; ++col) {
                    const v2f* g1  = col ? rB1  : rA1;
                    const v2f* g2  = col ? rB2  : rA2;
                    const v2f* g11 = col ? rB11 : rA11;
                    const v2f* g22 = col ? rB22 : rA22;
                    const v2f* g12 = col ? rB12 : rA12;
                    v2f sx1={0,0}, sy1={0,0}, sx2={0,0}, sy2={0,0};
                    v2f sx11={0,0}, sy11={0,0}, sx22={0,0}, sy22={0,0};
                    v2f sx12={0,0}, sy12={0,0};
#pragma unroll
                    for (int m = 0; m < 6; ++m) {
                        const int q = (j + 1 + m) % 6;
                        const v2f wx = { GWp[2*m + 1], GWp[2*m + 2] };
                        const v2f wy = { GWp[2*m],     GWp[2*m + 1] };
                        sx1  = __builtin_elementwise_fma(wx, g1[q],  sx1);
                        sy1  = __builtin_elementwise_fma(wy, g1[q],  sy1);
                        sx2  = __builtin_elementwise_fma(wx, g2[q],  sx2);
                        sy2  = __builtin_elementwise_fma(wy, g2[q],  sy2);
                        sx11 = __builtin_elementwise_fma(wx, g11[q], sx11);
                        sy11 = __builtin_elementwise_fma(wy, g11[q], sy11);
                        sx22 = __builtin_elementwise_fma(wx, g22[q], sx22);
                        sy22 = __builtin_elementwise_fma(wy, g22[q], sy22);
                        sx12 = __builtin_elementwise_fma(wx, g12[q], sx12);
                        sy12 = __builtin_elementwise_fma(wy, g12[q], sy12);
                    }
                    const v2f m1  = { sx1.x + sx1.y,  sy1.x + sy1.y };
                    const v2f m2  = { sx2.x + sx2.y,  sy2.x + sy2.y };
                    const v2f e11 = { sx11.x + sx11.y, sy11.x + sy11.y };
                    const v2f e22 = { sx22.x + sx22.y, sy22.x + sy22.y };
                    const v2f e12 = { sx12.x + sx12.y, sy12.x + sy12.y };

                    const v2f mu11 = m1 * m1;
                    const v2f mu22 = m2 * m2;
                    const v2f mu12 = m1 * m2;
                    const v2f zero = {0.0f, 0.0f};
                    const v2f one  = {1.0f, 1.0f};
                    const v2f sg1  = __builtin_elementwise_max(e11 - mu11, zero);
                    const v2f sg2  = __builtin_elementwise_max(e22 - mu22, zero);
                    const v2f sg12 = e12 - mu12;
                    const v2f num = (2.0f * mu12 + 1e-4f) * (2.0f * sg12 + 9e-4f);
                    const v2f den = (mu11 + mu22 + 1e-4f) * (sg1 + sg2 + 9e-4f);
                    v2f v = { num.x * __builtin_amdgcn_rcpf(den.x),
                              num.y * __builtin_amdgcn_rcpf(den.y) };
                    v = __builtin_elementwise_min(
                            __builtin_elementwise_max(v, zero), one);
                    accv += v;
                }
            }
        }
    }

    float acc = accv.x + accv.y;
#pragma unroll
    for (int off = 32; off > 0; off >>= 1)
        acc += __shfl_down(acc, off, 64);
    if ((tid & 63) == 0) wsum[tid >> 6] = acc;
    __syncthreads();
    if (tid == 0) {
        double blocksum = 0.0;
#pragma unroll
        for (int w = 0; w < TPB / 64; ++w) blocksum += (double)wsum[w];
        const int bid = blockIdx.x + (IMG / SH) * blockIdx.y;
        partial[bid] = blocksum;   // every slot written: no init needed
    }
}

__global__ __launch_bounds__(256) void ssim_finalize_kernel(
    const double* __restrict__ partial, float* __restrict__ out)
{
    __shared__ double wsum[4];
    const int tid = threadIdx.x;
    double s = 0.0;
#pragma unroll
    for (int k = 0; k < NBLK / 256; ++k) s += partial[tid + 256 * k];
#pragma unroll
    for (int off = 32; off > 0; off >>= 1)
        s += __shfl_down(s, off, 64);
    if ((tid & 63) == 0) wsum[tid >> 6] = s;
    __syncthreads();
    if (tid == 0) {
        double t = wsum[0] + wsum[1] + wsum[2] + wsum[3];
        out[0] = 1.0f - (float)(t / N_PIX);
    }
}

extern "C" void kernel_launch(void* const* d_in, const int* in_sizes, int n_in,
                              void* d_out, int out_size, void* d_ws, size_t ws_size,
                              hipStream_t stream) {
    const float* img1 = (const float*)d_in[0];
    const float* img2 = (const float*)d_in[1];
    float* out = (float*)d_out;
    double* parts = (double*)d_ws;   // 1536 doubles = 12 KB

    dim3 grid(IMG / SH, PLANES);     // 16 x 96 = 1536 blocks (full-width tiles)
    ssim_map_kernel<<<grid, TPB, 0, stream>>>(img1, img2, parts);
    ssim_finalize_kernel<<<1, 256, 0, stream>>>(parts, out);
}